// Round 5
// baseline (1015.429 us; speedup 1.0000x reference)
//
#include <hip/hip_runtime.h>

// Composite-filter formulation:
//   out[o] = sum_{k=0..54} Cp[r][k] * x[n0 - k],
//     r = (2o+32) % 3, n0 = (2o+32-r)/3,
//     Cp[p][k] = C[p+3k], C[j] = sum_m b[m]*h[j-2m]
//
// R7: direct-global windows: 46us, VALUBusy 22% -> stalled, not VALU-bound.
// R8 FAILED: reg double-buffer, VGPR 128, occupancy halved, 77us.
//   Lesson: latency hiding here comes from TLP (8 waves/SIMD at <=64 VGPR).
// R9: LDS tile + XOR float4-slot swizzle slot(c)=c^((c>>3)&7), 6-reg
//   rotating window. fused < 42.6us.
// R10 FAILED: megakernel w/ LDS coeff table: per-lane ds_read_b128 of
//   uniform addresses is NOT a free broadcast (5.2M conflict-cycles), and
//   path-merging pushed VGPR to 144 (occupancy 10%). 94us.
//   Lessons: keep paths split; uniform LDS reads serialize.
// R11: prep merge (3 dispatches -> 2). total 117 -> 108.9.
// R12: coeff fetches moved s_load -> vector global_load via opaque VGPR zero.
//   Theory: s_load deps need lgkmcnt(0) (SMEM is OOO) which drains the
//   ds_read window prefetches ~14x per wave. vmcnt is in-order/countable;
//   putting coeffs there (L1-hot 672B table) un-conflates the two pipelines.
//   __launch_bounds__(256,6) caps VGPR at 84 to stop loop-invariant hoisting.

#define TPB 256
#define RPT 12                    // outputs per thread
#define OTILE (TPB * RPT)         // 3072 outputs per block
#define NCHUNK 528                // float4 chunks staged per tile (2112 floats)
#define NTAPS 55
#define CPSTRIDE 56               // phase-major coeff stride (float4-aligned)

#define SLOT(c) ((c) ^ (((c) >> 3) & 7))

// One dispatch, 3 independent blocks:
//   block 0: build cp[3*56] composite coefficients (same order as R9 -> bit-identical)
//   block 1: head boundary (o in [0,50))
//   block 2: tail boundary (o in [n_out, out_size))
__global__ __launch_bounds__(TPB) void prep_k(
    const float* __restrict__ x, const float* __restrict__ h,
    const float* __restrict__ b, float* __restrict__ cp,
    float* __restrict__ out, int n_in, int n_out, int out_size)
{
    __shared__ float h_s[63];
    __shared__ float b_s[51];
    __shared__ float x_s[64];
    __shared__ float u_s[50];

    const int tid = threadIdx.x;
    if (tid < 63) h_s[tid] = h[tid];
    if (tid < 51) b_s[tid] = b[tid];

    if (blockIdx.x == 0) {
        __syncthreads();
        for (int idx = tid; idx < 3 * CPSTRIDE; idx += TPB) {
            const int p = idx / CPSTRIDE;
            const int k = idx - p * CPSTRIDE;
            float acc = 0.0f;
            if (k < NTAPS) {
                const int j = p + 3 * k;
                for (int m = 0; m <= 50; ++m) {
                    const int hi = j - 2 * m;
                    if (hi >= 0 && hi <= 62) acc += b_s[m] * h_s[hi];
                }
            }
            cp[idx] = acc;
        }
    } else if (blockIdx.x == 1) {
        if (tid < 44) x_s[tid] = (tid < n_in) ? x[tid] : 0.0f;
        __syncthreads();
        if (tid < 50) {
            const int s  = 2 * tid + 32;
            const int p0 = s % 3;
            const int q  = s / 3;
            float u = 0.0f;
            #pragma unroll
            for (int i = 0; i <= 20; ++i) {
                const int xi = q - i;
                u += h_s[p0 + 3 * i] * ((xi >= 0) ? x_s[xi] : 0.0f);
            }
            u_s[tid] = u;
        }
        __syncthreads();
        if (tid < 50) {
            float acc = 0.0f;
            for (int t = 0; t <= tid; ++t) acc += b_s[tid - t] * u_s[t];
            out[tid] = acc;
        }
    } else {
        const int t0   = n_out - 50;
        const int qmin = (2 * t0 + 32) / 3;
        const int xb   = qmin - 20;
        if (tid < 64) {
            const int xi = xb + tid;
            x_s[tid] = (xi >= 0 && xi < n_in) ? x[xi] : 0.0f;
        }
        __syncthreads();
        if (tid < 50) {
            const int t  = t0 + tid;
            const int s  = 2 * t + 32;
            const int p0 = s % 3;
            const int q  = s / 3;
            const int base = q - xb;
            float u = 0.0f;
            #pragma unroll
            for (int i = 0; i <= 20; ++i)
                u += h_s[p0 + 3 * i] * x_s[base - i];
            u_s[tid] = u;
        }
        __syncthreads();
        const int n_tail = out_size - n_out;   // 96
        if (tid < n_tail) {
            float acc = 0.0f;
            for (int j = tid; j <= 49; ++j) acc += b_s[tid + 50 - j] * u_s[j];
            out[n_out + tid] = acc;
        }
    }
}

// Group g covers taps k=4g..4g+3 for 12 outputs d=0..11.
// delta_d = {0,1,2,2,3,4,4,5,6,6,7,8}, phase r_d = (2+2d)%3 -> q2/q1/q0 cycle.
// Window float (54+delta-4g-j) -> chunks: A=w[15-g], B=w[14-g], C=w[13-g], D=w[12-g].
// zz is an opaque VGPR 0: forces coeff loads onto the vector/vmcnt path.
#define GRP12(g, A, B, C, D) {                                          \
    const float4 q2 = c2q[(g) + zz];                                    \
    const float4 q1 = c1q[(g) + zz];                                    \
    const float4 q0 = c0q[(g) + zz];                                    \
    /* j=0 */                                                           \
    a0  += q2.x * C.z;  a1  += q1.x * C.w;  a2  += q0.x * B.x;          \
    a3  += q2.x * B.x;  a4  += q1.x * B.y;  a5  += q0.x * B.z;          \
    a6  += q2.x * B.z;  a7  += q1.x * B.w;  a8  += q0.x * A.x;          \
    a9  += q2.x * A.x;  a10 += q1.x * A.y;  a11 += q0.x * A.z;          \
    /* j=1 */                                                           \
    a0  += q2.y * C.y;  a1  += q1.y * C.z;  a2  += q0.y * C.w;          \
    a3  += q2.y * C.w;  a4  += q1.y * B.x;  a5  += q0.y * B.y;          \
    a6  += q2.y * B.y;  a7  += q1.y * B.z;  a8  += q0.y * B.w;          \
    a9  += q2.y * B.w;  a10 += q1.y * A.x;  a11 += q0.y * A.y;          \
    /* j=2 */                                                           \
    a0  += q2.z * C.x;  a1  += q1.z * C.y;  a2  += q0.z * C.z;          \
    a3  += q2.z * C.z;  a4  += q1.z * C.w;  a5  += q0.z * B.x;          \
    a6  += q2.z * B.x;  a7  += q1.z * B.y;  a8  += q0.z * B.z;          \
    a9  += q2.z * B.z;  a10 += q1.z * B.w;  a11 += q0.z * A.x;          \
    /* j=3 */                                                           \
    a0  += q2.w * D.w;  a1  += q1.w * C.x;  a2  += q0.w * C.y;          \
    a3  += q2.w * C.y;  a4  += q1.w * C.z;  a5  += q0.w * C.w;          \
    a6  += q2.w * C.w;  a7  += q1.w * B.x;  a8  += q0.w * B.y;          \
    a9  += q2.w * B.y;  a10 += q1.w * B.z;  a11 += q0.w * B.w; }

// Tail group: j=0..2 only (k = 52,53,54).
#define GRP12T(g, A, B, C) {                                            \
    const float4 q2 = c2q[(g) + zz];                                    \
    const float4 q1 = c1q[(g) + zz];                                    \
    const float4 q0 = c0q[(g) + zz];                                    \
    a0  += q2.x * C.z;  a1  += q1.x * C.w;  a2  += q0.x * B.x;          \
    a3  += q2.x * B.x;  a4  += q1.x * B.y;  a5  += q0.x * B.z;          \
    a6  += q2.x * B.z;  a7  += q1.x * B.w;  a8  += q0.x * A.x;          \
    a9  += q2.x * A.x;  a10 += q1.x * A.y;  a11 += q0.x * A.z;          \
    a0  += q2.y * C.y;  a1  += q1.y * C.z;  a2  += q0.y * C.w;          \
    a3  += q2.y * C.w;  a4  += q1.y * B.x;  a5  += q0.y * B.y;          \
    a6  += q2.y * B.y;  a7  += q1.y * B.z;  a8  += q0.y * B.w;          \
    a9  += q2.y * B.w;  a10 += q1.y * A.x;  a11 += q0.y * A.y;          \
    a0  += q2.z * C.x;  a1  += q1.z * C.y;  a2  += q0.z * C.z;          \
    a3  += q2.z * C.z;  a4  += q1.z * C.w;  a5  += q0.z * B.x;          \
    a6  += q2.z * B.x;  a7  += q1.z * B.y;  a8  += q0.z * B.z;          \
    a9  += q2.z * B.z;  a10 += q1.z * B.w;  a11 += q0.z * A.x; }

__global__ __launch_bounds__(TPB, 6) void fused_fast(
    const float* __restrict__ x, const float* __restrict__ cp,
    float* __restrict__ out, int n_in, int n_out)
{
    __shared__ float4 xs4[NCHUNK];   // 8448 B, XOR-swizzled float4 slots

    const int tid = threadIdx.x;
    const int bt  = blockIdx.x;
    const int o0  = bt * OTILE;                  // multiple of 3072
    const int n_tile0 = 2048 * bt - 44;          // tile x-base, multiple of 4

    // Opaque VGPR zero: makes coeff addresses unprovably-uniform so the
    // compiler emits global_load_dwordx4 (vmcnt, in-order, countable waits)
    // instead of s_load (lgkmcnt(0) full drains that stall the ds window).
    int zz = 0;
    asm volatile("" : "+v"(zz));

    const float4* c2q = (const float4*)(cp + 2 * CPSTRIDE);  // phase 2 (o%3==0)
    const float4* c1q = (const float4*)(cp + 1 * CPSTRIDE);
    const float4* c0q = (const float4*)(cp + 0 * CPSTRIDE);

    // ---- stage tile into LDS (swizzled slots) ----
    // interior: staging reads [n_tile0, n_tile0 + 2112) fully inside x
    const bool interior = (n_tile0 >= 0) && (n_tile0 + 4 * NCHUNK <= n_in);
    if (interior) {
        const float4* gx = (const float4*)(x + n_tile0);
        const float4 g0 = gx[tid];
        const float4 g1 = gx[tid + 256];
        xs4[SLOT(tid)]       = g0;
        xs4[SLOT(tid + 256)] = g1;
        if (tid < NCHUNK - 512) {
            xs4[SLOT(tid + 512)] = gx[tid + 512];
        }
    } else {
        float* xsf = (float*)xs4;
        for (int i = tid; i < 4 * NCHUNK; i += TPB) {
            const int n = n_tile0 + i;
            const float v = (n >= 0 && n < n_in) ? x[n] : 0.0f;
            xsf[(SLOT(i >> 2) << 2) | (i & 3)] = v;
        }
    }
    __syncthreads();

    float a0 = 0.f, a1 = 0.f, a2 = 0.f, a3  = 0.f, a4  = 0.f, a5  = 0.f;
    float a6 = 0.f, a7 = 0.f, a8 = 0.f, a9  = 0.f, a10 = 0.f, a11 = 0.f;

    // ---- compute: 6-reg rotating window over chunks cbase+15 .. cbase+0 ----
    // XS(j) = tile chunk (2*tid + j), swizzled.
    const int cbase = 2 * tid;
#define XS(j) xs4[SLOT(cbase + (j))]
    {
        float4 r0 = XS(15), r1 = XS(14), r2 = XS(13),
               r3 = XS(12), r4 = XS(11), r5 = XS(10);
        GRP12( 0, r0, r1, r2, r3);  r0 = XS(9);
        GRP12( 1, r1, r2, r3, r4);  r1 = XS(8);
        GRP12( 2, r2, r3, r4, r5);  r2 = XS(7);
        GRP12( 3, r3, r4, r5, r0);  r3 = XS(6);
        GRP12( 4, r4, r5, r0, r1);  r4 = XS(5);
        GRP12( 5, r5, r0, r1, r2);  r5 = XS(4);
        GRP12( 6, r0, r1, r2, r3);  r0 = XS(3);
        GRP12( 7, r1, r2, r3, r4);  r1 = XS(2);
        GRP12( 8, r2, r3, r4, r5);  r2 = XS(1);
        GRP12( 9, r3, r4, r5, r0);  r3 = XS(0);
        GRP12(10, r4, r5, r0, r1);
        GRP12(11, r5, r0, r1, r2);
        GRP12(12, r0, r1, r2, r3);
        GRP12T(13, r1, r2, r3);
    }
#undef XS

    // ---- store 12 outputs ----
    const int ob = o0 + RPT * tid;               // multiple of 12
    if (ob >= 50 && ob + 11 < n_out) {
        float4* o4 = (float4*)(out + ob);        // 16B aligned (ob % 4 == 0)
        o4[0] = make_float4(a0, a1, a2,  a3);
        o4[1] = make_float4(a4, a5, a6,  a7);
        o4[2] = make_float4(a8, a9, a10, a11);
    } else {
        const float accs[RPT] = {a0, a1, a2, a3, a4, a5, a6, a7, a8, a9, a10, a11};
#pragma unroll
        for (int d = 0; d < RPT; ++d) {
            const int o = ob + d;
            if (o >= 50 && o < n_out) out[o] = accs[d];
        }
    }
}

extern "C" void kernel_launch(void* const* d_in, const int* in_sizes, int n_in_arrs,
                              void* d_out, int out_size, void* d_ws, size_t ws_size,
                              hipStream_t stream) {
    const float* x = (const float*)d_in[0];
    const float* h = (const float*)d_in[1];
    const float* b = (const float*)d_in[2];
    float* out = (float*)d_out;
    float* cp  = (float*)d_ws;                        // 3*56*4 = 672 bytes

    const int n_in  = in_sizes[0];                    // 8388608
    const int n_out = (int)((long long)n_in * 3 / 2); // 12582912

    prep_k<<<3, TPB, 0, stream>>>(x, h, b, cp, out, n_in, n_out, out_size);

    const int nblocks = (n_out + OTILE - 1) / OTILE;  // 4096
    fused_fast<<<nblocks, TPB, 0, stream>>>(x, cp, out, n_in, n_out);
}

// Round 6
// 113.295 us; speedup vs baseline: 8.9627x; 8.9627x over previous
//
#include <hip/hip_runtime.h>

// Composite-filter formulation:
//   out[o] = sum_{k=0..54} Cp[r][k] * x[n0 - k],
//     r = (2o+32) % 3, n0 = (2o+32-r)/3,
//     Cp[p][k] = C[p+3k], C[j] = sum_m b[m]*h[j-2m]
//
// R7: direct-global windows, up-front 16-load burst: 46us, VALUBusy 22%.
// R8 FAILED: reg double-buffer, VGPR 128, occupancy halved, 77us.
//   Lesson: latency hiding here comes from TLP (8 waves/SIMD at <=64 VGPR).
// R9: LDS tile + XOR float4-slot swizzle slot(c)=c^((c>>3)&7), 6-reg
//   rotating window. fused < 42.6us.
// R10 FAILED: LDS coeff table (uniform ds_read_b128 is NOT free broadcast,
//   5.2M conflict-cy) + path merge (VGPR 144). Keep coeffs in SGPRs.
// R11: prep merge (3 dispatches -> 2). total 117 -> 108.9. (best)
// R12 FAILED: opaque-VGPR coeff index + launch_bounds cap -> scratch spills
//   (FETCH 1.35GB, WRITE 2.1GB, 946us). Lesson: WRITE_SIZE explosion = spill
//   detector; never combine codegen tricks with occupancy caps.
// R13: R11 + window read as ONE up-front burst of 16 ds_read_b128 (R7's
//   register structure, LDS source). Leaves a single lgkmcnt drain point;
//   coeff s_load lgkmcnt(0) waits no longer drain in-flight window reads
//   (SMEM is OOO -> full-counter drain; ds interleave made each one a stall).

#define TPB 256
#define RPT 12                    // outputs per thread
#define OTILE (TPB * RPT)         // 3072 outputs per block
#define NCHUNK 528                // float4 chunks staged per tile (2112 floats)
#define NTAPS 55
#define CPSTRIDE 56               // phase-major coeff stride (float4-aligned)

#define SLOT(c) ((c) ^ (((c) >> 3) & 7))

// One dispatch, 3 independent blocks:
//   block 0: build cp[3*56] composite coefficients (same order -> bit-identical)
//   block 1: head boundary (o in [0,50))
//   block 2: tail boundary (o in [n_out, out_size))
__global__ __launch_bounds__(TPB) void prep_k(
    const float* __restrict__ x, const float* __restrict__ h,
    const float* __restrict__ b, float* __restrict__ cp,
    float* __restrict__ out, int n_in, int n_out, int out_size)
{
    __shared__ float h_s[63];
    __shared__ float b_s[51];
    __shared__ float x_s[64];
    __shared__ float u_s[50];

    const int tid = threadIdx.x;
    if (tid < 63) h_s[tid] = h[tid];
    if (tid < 51) b_s[tid] = b[tid];

    if (blockIdx.x == 0) {
        __syncthreads();
        for (int idx = tid; idx < 3 * CPSTRIDE; idx += TPB) {
            const int p = idx / CPSTRIDE;
            const int k = idx - p * CPSTRIDE;
            float acc = 0.0f;
            if (k < NTAPS) {
                const int j = p + 3 * k;
                for (int m = 0; m <= 50; ++m) {
                    const int hi = j - 2 * m;
                    if (hi >= 0 && hi <= 62) acc += b_s[m] * h_s[hi];
                }
            }
            cp[idx] = acc;
        }
    } else if (blockIdx.x == 1) {
        if (tid < 44) x_s[tid] = (tid < n_in) ? x[tid] : 0.0f;
        __syncthreads();
        if (tid < 50) {
            const int s  = 2 * tid + 32;
            const int p0 = s % 3;
            const int q  = s / 3;
            float u = 0.0f;
            #pragma unroll
            for (int i = 0; i <= 20; ++i) {
                const int xi = q - i;
                u += h_s[p0 + 3 * i] * ((xi >= 0) ? x_s[xi] : 0.0f);
            }
            u_s[tid] = u;
        }
        __syncthreads();
        if (tid < 50) {
            float acc = 0.0f;
            for (int t = 0; t <= tid; ++t) acc += b_s[tid - t] * u_s[t];
            out[tid] = acc;
        }
    } else {
        const int t0   = n_out - 50;
        const int qmin = (2 * t0 + 32) / 3;
        const int xb   = qmin - 20;
        if (tid < 64) {
            const int xi = xb + tid;
            x_s[tid] = (xi >= 0 && xi < n_in) ? x[xi] : 0.0f;
        }
        __syncthreads();
        if (tid < 50) {
            const int t  = t0 + tid;
            const int s  = 2 * t + 32;
            const int p0 = s % 3;
            const int q  = s / 3;
            const int base = q - xb;
            float u = 0.0f;
            #pragma unroll
            for (int i = 0; i <= 20; ++i)
                u += h_s[p0 + 3 * i] * x_s[base - i];
            u_s[tid] = u;
        }
        __syncthreads();
        const int n_tail = out_size - n_out;   // 96
        if (tid < n_tail) {
            float acc = 0.0f;
            for (int j = tid; j <= 49; ++j) acc += b_s[tid + 50 - j] * u_s[j];
            out[n_out + tid] = acc;
        }
    }
}

// Group g covers taps k=4g..4g+3 for 12 outputs d=0..11.
// delta_d = {0,1,2,2,3,4,4,5,6,6,7,8}, phase r_d = (2+2d)%3 -> q2/q1/q0 cycle.
// Window float (54+delta-4g-j) -> chunks: A=w[15-g], B=w[14-g], C=w[13-g], D=w[12-g].
#define GRP12(g, A, B, C, D) {                                          \
    const float4 q2 = c2q[g];                                           \
    const float4 q1 = c1q[g];                                           \
    const float4 q0 = c0q[g];                                           \
    /* j=0 */                                                           \
    a0  += q2.x * C.z;  a1  += q1.x * C.w;  a2  += q0.x * B.x;          \
    a3  += q2.x * B.x;  a4  += q1.x * B.y;  a5  += q0.x * B.z;          \
    a6  += q2.x * B.z;  a7  += q1.x * B.w;  a8  += q0.x * A.x;          \
    a9  += q2.x * A.x;  a10 += q1.x * A.y;  a11 += q0.x * A.z;          \
    /* j=1 */                                                           \
    a0  += q2.y * C.y;  a1  += q1.y * C.z;  a2  += q0.y * C.w;          \
    a3  += q2.y * C.w;  a4  += q1.y * B.x;  a5  += q0.y * B.y;          \
    a6  += q2.y * B.y;  a7  += q1.y * B.z;  a8  += q0.y * B.w;          \
    a9  += q2.y * B.w;  a10 += q1.y * A.x;  a11 += q0.y * A.y;          \
    /* j=2 */                                                           \
    a0  += q2.z * C.x;  a1  += q1.z * C.y;  a2  += q0.z * C.z;          \
    a3  += q2.z * C.z;  a4  += q1.z * C.w;  a5  += q0.z * B.x;          \
    a6  += q2.z * B.x;  a7  += q1.z * B.y;  a8  += q0.z * B.z;          \
    a9  += q2.z * B.z;  a10 += q1.z * B.w;  a11 += q0.z * A.x;          \
    /* j=3 */                                                           \
    a0  += q2.w * D.w;  a1  += q1.w * C.x;  a2  += q0.w * C.y;          \
    a3  += q2.w * C.y;  a4  += q1.w * C.z;  a5  += q0.w * C.w;          \
    a6  += q2.w * C.w;  a7  += q1.w * B.x;  a8  += q0.w * B.y;          \
    a9  += q2.w * B.y;  a10 += q1.w * B.z;  a11 += q0.w * B.w; }

// Tail group: j=0..2 only (k = 52,53,54).
#define GRP12T(g, A, B, C) {                                            \
    const float4 q2 = c2q[g];                                           \
    const float4 q1 = c1q[g];                                           \
    const float4 q0 = c0q[g];                                           \
    a0  += q2.x * C.z;  a1  += q1.x * C.w;  a2  += q0.x * B.x;          \
    a3  += q2.x * B.x;  a4  += q1.x * B.y;  a5  += q0.x * B.z;          \
    a6  += q2.x * B.z;  a7  += q1.x * B.w;  a8  += q0.x * A.x;          \
    a9  += q2.x * A.x;  a10 += q1.x * A.y;  a11 += q0.x * A.z;          \
    a0  += q2.y * C.y;  a1  += q1.y * C.z;  a2  += q0.y * C.w;          \
    a3  += q2.y * C.w;  a4  += q1.y * B.x;  a5  += q0.y * B.y;          \
    a6  += q2.y * B.y;  a7  += q1.y * B.z;  a8  += q0.y * B.w;          \
    a9  += q2.y * B.w;  a10 += q1.y * A.x;  a11 += q0.y * A.y;          \
    a0  += q2.z * C.x;  a1  += q1.z * C.y;  a2  += q0.z * C.z;          \
    a3  += q2.z * C.z;  a4  += q1.z * C.w;  a5  += q0.z * B.x;          \
    a6  += q2.z * B.x;  a7  += q1.z * B.y;  a8  += q0.z * B.z;          \
    a9  += q2.z * B.z;  a10 += q1.z * B.w;  a11 += q0.z * A.x; }

__global__ __launch_bounds__(TPB) void fused_fast(
    const float* __restrict__ x, const float* __restrict__ cp,
    float* __restrict__ out, int n_in, int n_out)
{
    __shared__ float4 xs4[NCHUNK];   // 8448 B, XOR-swizzled float4 slots

    const int tid = threadIdx.x;
    const int bt  = blockIdx.x;
    const int o0  = bt * OTILE;                  // multiple of 3072
    const int n_tile0 = 2048 * bt - 44;          // tile x-base, multiple of 4

    const float4* c2q = (const float4*)(cp + 2 * CPSTRIDE);  // phase 2 (o%3==0)
    const float4* c1q = (const float4*)(cp + 1 * CPSTRIDE);
    const float4* c0q = (const float4*)(cp + 0 * CPSTRIDE);

    // ---- stage tile into LDS (swizzled slots) ----
    // interior: staging reads [n_tile0, n_tile0 + 2112) fully inside x
    const bool interior = (n_tile0 >= 0) && (n_tile0 + 4 * NCHUNK <= n_in);
    if (interior) {
        const float4* gx = (const float4*)(x + n_tile0);
        const float4 g0 = gx[tid];
        const float4 g1 = gx[tid + 256];
        xs4[SLOT(tid)]       = g0;
        xs4[SLOT(tid + 256)] = g1;
        if (tid < NCHUNK - 512) {
            xs4[SLOT(tid + 512)] = gx[tid + 512];
        }
    } else {
        float* xsf = (float*)xs4;
        for (int i = tid; i < 4 * NCHUNK; i += TPB) {
            const int n = n_tile0 + i;
            const float v = (n >= 0 && n < n_in) ? x[n] : 0.0f;
            xsf[(SLOT(i >> 2) << 2) | (i & 3)] = v;
        }
    }
    __syncthreads();

    float a0 = 0.f, a1 = 0.f, a2 = 0.f, a3  = 0.f, a4  = 0.f, a5  = 0.f;
    float a6 = 0.f, a7 = 0.f, a8 = 0.f, a9  = 0.f, a10 = 0.f, a11 = 0.f;

    // ---- compute: single up-front burst of all 16 window chunks ----
    // One lgkmcnt drain point (the sched_barrier boundary); the FMA stream
    // after it contains no ds ops, so coeff s_load lgkmcnt(0) waits are cheap.
    const int cbase = 2 * tid;
#define XS(j) xs4[SLOT(cbase + (j))]
    {
        const float4 w15 = XS(15); const float4 w14 = XS(14);
        const float4 w13 = XS(13); const float4 w12 = XS(12);
        const float4 w11 = XS(11); const float4 w10 = XS(10);
        const float4 w9  = XS(9);  const float4 w8  = XS(8);
        const float4 w7  = XS(7);  const float4 w6  = XS(6);
        const float4 w5  = XS(5);  const float4 w4  = XS(4);
        const float4 w3  = XS(3);  const float4 w2  = XS(2);
        const float4 w1  = XS(1);  const float4 w0  = XS(0);
        __builtin_amdgcn_sched_barrier(0);
        GRP12( 0, w15, w14, w13, w12);
        GRP12( 1, w14, w13, w12, w11);
        GRP12( 2, w13, w12, w11, w10);
        GRP12( 3, w12, w11, w10, w9);
        GRP12( 4, w11, w10, w9,  w8);
        GRP12( 5, w10, w9,  w8,  w7);
        GRP12( 6, w9,  w8,  w7,  w6);
        GRP12( 7, w8,  w7,  w6,  w5);
        GRP12( 8, w7,  w6,  w5,  w4);
        GRP12( 9, w6,  w5,  w4,  w3);
        GRP12(10, w5,  w4,  w3,  w2);
        GRP12(11, w4,  w3,  w2,  w1);
        GRP12(12, w3,  w2,  w1,  w0);
        GRP12T(13, w2, w1, w0);
    }
#undef XS

    // ---- store 12 outputs ----
    const int ob = o0 + RPT * tid;               // multiple of 12
    if (ob >= 50 && ob + 11 < n_out) {
        float4* o4 = (float4*)(out + ob);        // 16B aligned (ob % 4 == 0)
        o4[0] = make_float4(a0, a1, a2,  a3);
        o4[1] = make_float4(a4, a5, a6,  a7);
        o4[2] = make_float4(a8, a9, a10, a11);
    } else {
        const float accs[RPT] = {a0, a1, a2, a3, a4, a5, a6, a7, a8, a9, a10, a11};
#pragma unroll
        for (int d = 0; d < RPT; ++d) {
            const int o = ob + d;
            if (o >= 50 && o < n_out) out[o] = accs[d];
        }
    }
}

extern "C" void kernel_launch(void* const* d_in, const int* in_sizes, int n_in_arrs,
                              void* d_out, int out_size, void* d_ws, size_t ws_size,
                              hipStream_t stream) {
    const float* x = (const float*)d_in[0];
    const float* h = (const float*)d_in[1];
    const float* b = (const float*)d_in[2];
    float* out = (float*)d_out;
    float* cp  = (float*)d_ws;                        // 3*56*4 = 672 bytes

    const int n_in  = in_sizes[0];                    // 8388608
    const int n_out = (int)((long long)n_in * 3 / 2); // 12582912

    prep_k<<<3, TPB, 0, stream>>>(x, h, b, cp, out, n_in, n_out, out_size);

    const int nblocks = (n_out + OTILE - 1) / OTILE;  // 4096
    fused_fast<<<nblocks, TPB, 0, stream>>>(x, cp, out, n_in, n_out);
}

// Round 7
// 107.379 us; speedup vs baseline: 9.4565x; 1.0551x over previous
//
#include <hip/hip_runtime.h>

// Composite-filter formulation:
//   out[o] = sum_{k=0..54} Cp[r][k] * x[n0 - k],
//     r = (2o+32) % 3, n0 = (2o+32-r)/3,
//     Cp[p][k] = C[p+3k], C[j] = sum_m b[m]*h[j-2m]
//
// R7: direct-global windows, no barrier: 46us, VALUBusy 22%.
// R8 FAILED: reg double-buffer, VGPR 128, occupancy halved, 77us.
//   Lesson: latency hiding here comes from TLP (8 waves/SIMD at <=64 VGPR).
// R9: LDS tile + XOR float4-slot swizzle slot(c)=c^((c>>3)&7), 6-reg
//   rotating window, block barrier. fused < 42.6us.
// R10 FAILED: LDS coeff table (uniform ds_read_b128 is NOT free broadcast)
//   + path merge (VGPR 144). Keep coeffs in SGPRs via global cp.
// R11: prep merge (3 dispatches -> 2). total 117 -> 108.9. (best)
// R12 FAILED: opaque-VGPR coeff index + launch_bounds cap -> scratch spills.
//   Lesson: WRITE_SIZE explosion = spill detector.
// R13: single up-front ds burst: 113.3 ~ neutral. lgkmcnt-conflation REFUTED.
// R14: wave-autonomous staging. Each wave stages its own 142 chunks into a
//   private 144-slot swizzled LDS region (lane l loads chunks l, l+64, and
//   l+128 if l<14); compute reads only own-region -> in-wave lgkmcnt waits
//   suffice, __syncthreads DELETED (edge blocks use guarded loads, same
//   structure). Combines R9's L1 dedup with R7's wave autonomy: removes the
//   4-wave barrier coupling paid at every one of ~16 block-turnovers/CU.

#define TPB 256
#define RPT 12                    // outputs per thread
#define OTILE (TPB * RPT)         // 3072 outputs per block
#define WREG 144                  // float4 slots per wave region (144%8==0)
#define NTAPS 55
#define CPSTRIDE 56               // phase-major coeff stride (float4-aligned)

#define SLOT(c) ((c) ^ (((c) >> 3) & 7))

// One dispatch, 3 independent blocks:
//   block 0: build cp[3*56] composite coefficients (same order -> bit-identical)
//   block 1: head boundary (o in [0,50))
//   block 2: tail boundary (o in [n_out, out_size))
__global__ __launch_bounds__(TPB) void prep_k(
    const float* __restrict__ x, const float* __restrict__ h,
    const float* __restrict__ b, float* __restrict__ cp,
    float* __restrict__ out, int n_in, int n_out, int out_size)
{
    __shared__ float h_s[63];
    __shared__ float b_s[51];
    __shared__ float x_s[64];
    __shared__ float u_s[50];

    const int tid = threadIdx.x;
    if (tid < 63) h_s[tid] = h[tid];
    if (tid < 51) b_s[tid] = b[tid];

    if (blockIdx.x == 0) {
        __syncthreads();
        for (int idx = tid; idx < 3 * CPSTRIDE; idx += TPB) {
            const int p = idx / CPSTRIDE;
            const int k = idx - p * CPSTRIDE;
            float acc = 0.0f;
            if (k < NTAPS) {
                const int j = p + 3 * k;
                for (int m = 0; m <= 50; ++m) {
                    const int hi = j - 2 * m;
                    if (hi >= 0 && hi <= 62) acc += b_s[m] * h_s[hi];
                }
            }
            cp[idx] = acc;
        }
    } else if (blockIdx.x == 1) {
        if (tid < 44) x_s[tid] = (tid < n_in) ? x[tid] : 0.0f;
        __syncthreads();
        if (tid < 50) {
            const int s  = 2 * tid + 32;
            const int p0 = s % 3;
            const int q  = s / 3;
            float u = 0.0f;
            #pragma unroll
            for (int i = 0; i <= 20; ++i) {
                const int xi = q - i;
                u += h_s[p0 + 3 * i] * ((xi >= 0) ? x_s[xi] : 0.0f);
            }
            u_s[tid] = u;
        }
        __syncthreads();
        if (tid < 50) {
            float acc = 0.0f;
            for (int t = 0; t <= tid; ++t) acc += b_s[tid - t] * u_s[t];
            out[tid] = acc;
        }
    } else {
        const int t0   = n_out - 50;
        const int qmin = (2 * t0 + 32) / 3;
        const int xb   = qmin - 20;
        if (tid < 64) {
            const int xi = xb + tid;
            x_s[tid] = (xi >= 0 && xi < n_in) ? x[xi] : 0.0f;
        }
        __syncthreads();
        if (tid < 50) {
            const int t  = t0 + tid;
            const int s  = 2 * t + 32;
            const int p0 = s % 3;
            const int q  = s / 3;
            const int base = q - xb;
            float u = 0.0f;
            #pragma unroll
            for (int i = 0; i <= 20; ++i)
                u += h_s[p0 + 3 * i] * x_s[base - i];
            u_s[tid] = u;
        }
        __syncthreads();
        const int n_tail = out_size - n_out;   // 96
        if (tid < n_tail) {
            float acc = 0.0f;
            for (int j = tid; j <= 49; ++j) acc += b_s[tid + 50 - j] * u_s[j];
            out[n_out + tid] = acc;
        }
    }
}

// Group g covers taps k=4g..4g+3 for 12 outputs d=0..11.
// delta_d = {0,1,2,2,3,4,4,5,6,6,7,8}, phase r_d = (2+2d)%3 -> q2/q1/q0 cycle.
// Window float (54+delta-4g-j) -> chunks: A=w[15-g], B=w[14-g], C=w[13-g], D=w[12-g].
#define GRP12(g, A, B, C, D) {                                          \
    const float4 q2 = c2q[g];                                           \
    const float4 q1 = c1q[g];                                           \
    const float4 q0 = c0q[g];                                           \
    /* j=0 */                                                           \
    a0  += q2.x * C.z;  a1  += q1.x * C.w;  a2  += q0.x * B.x;          \
    a3  += q2.x * B.x;  a4  += q1.x * B.y;  a5  += q0.x * B.z;          \
    a6  += q2.x * B.z;  a7  += q1.x * B.w;  a8  += q0.x * A.x;          \
    a9  += q2.x * A.x;  a10 += q1.x * A.y;  a11 += q0.x * A.z;          \
    /* j=1 */                                                           \
    a0  += q2.y * C.y;  a1  += q1.y * C.z;  a2  += q0.y * C.w;          \
    a3  += q2.y * C.w;  a4  += q1.y * B.x;  a5  += q0.y * B.y;          \
    a6  += q2.y * B.y;  a7  += q1.y * B.z;  a8  += q0.y * B.w;          \
    a9  += q2.y * B.w;  a10 += q1.y * A.x;  a11 += q0.y * A.y;          \
    /* j=2 */                                                           \
    a0  += q2.z * C.x;  a1  += q1.z * C.y;  a2  += q0.z * C.z;          \
    a3  += q2.z * C.z;  a4  += q1.z * C.w;  a5  += q0.z * B.x;          \
    a6  += q2.z * B.x;  a7  += q1.z * B.y;  a8  += q0.z * B.z;          \
    a9  += q2.z * B.z;  a10 += q1.z * B.w;  a11 += q0.z * A.x;          \
    /* j=3 */                                                           \
    a0  += q2.w * D.w;  a1  += q1.w * C.x;  a2  += q0.w * C.y;          \
    a3  += q2.w * C.y;  a4  += q1.w * C.z;  a5  += q0.w * C.w;          \
    a6  += q2.w * C.w;  a7  += q1.w * B.x;  a8  += q0.w * B.y;          \
    a9  += q2.w * B.y;  a10 += q1.w * B.z;  a11 += q0.w * B.w; }

// Tail group: j=0..2 only (k = 52,53,54).
#define GRP12T(g, A, B, C) {                                            \
    const float4 q2 = c2q[g];                                           \
    const float4 q1 = c1q[g];                                           \
    const float4 q0 = c0q[g];                                           \
    a0  += q2.x * C.z;  a1  += q1.x * C.w;  a2  += q0.x * B.x;          \
    a3  += q2.x * B.x;  a4  += q1.x * B.y;  a5  += q0.x * B.z;          \
    a6  += q2.x * B.z;  a7  += q1.x * B.w;  a8  += q0.x * A.x;          \
    a9  += q2.x * A.x;  a10 += q1.x * A.y;  a11 += q0.x * A.z;          \
    a0  += q2.y * C.y;  a1  += q1.y * C.z;  a2  += q0.y * C.w;          \
    a3  += q2.y * C.w;  a4  += q1.y * B.x;  a5  += q0.y * B.y;          \
    a6  += q2.y * B.y;  a7  += q1.y * B.z;  a8  += q0.y * B.w;          \
    a9  += q2.y * B.w;  a10 += q1.y * A.x;  a11 += q0.y * A.y;          \
    a0  += q2.z * C.x;  a1  += q1.z * C.y;  a2  += q0.z * C.z;          \
    a3  += q2.z * C.z;  a4  += q1.z * C.w;  a5  += q0.z * B.x;          \
    a6  += q2.z * B.x;  a7  += q1.z * B.y;  a8  += q0.z * B.z;          \
    a9  += q2.z * B.z;  a10 += q1.z * B.w;  a11 += q0.z * A.x; }

__global__ __launch_bounds__(TPB) void fused_fast(
    const float* __restrict__ x, const float* __restrict__ cp,
    float* __restrict__ out, int n_in, int n_out)
{
    __shared__ float4 xs4[4 * WREG];   // 9216 B, per-wave swizzled regions

    const int tid = threadIdx.x;
    const int w   = tid >> 6;                    // wave id 0..3
    const int l   = tid & 63;                    // lane
    const int bt  = blockIdx.x;
    const int o0  = bt * OTILE;                  // multiple of 3072
    const int n_tile0 = 2048 * bt - 44;          // tile x-base, multiple of 4
    const int wreg = w * WREG;                   // this wave's LDS region base

    const float4* c2q = (const float4*)(cp + 2 * CPSTRIDE);  // phase 2 (o%3==0)
    const float4* c1q = (const float4*)(cp + 1 * CPSTRIDE);
    const float4* c0q = (const float4*)(cp + 0 * CPSTRIDE);

    // ---- wave-autonomous staging: lane l stages local chunks l, l+64,
    //      and (l<14) l+128 of this wave's 142-chunk window [0,141].
    //      Local chunk c' = tile chunk 128*w + c'. NO __syncthreads anywhere:
    //      compute reads only own-wave region; in-wave lgkmcnt orders it.
    // interior: max float read = n_tile0 + 4*(128*3 + 141) + 3 = n_tile0+2103
    const bool interior = (n_tile0 >= 0) && (n_tile0 + 2104 <= n_in);
    if (interior) {
        const float4* gw = (const float4*)(x + n_tile0) + 128 * w;
        const float4 g0 = gw[l];
        const float4 g1 = gw[l + 64];
        xs4[wreg + SLOT(l)]      = g0;
        xs4[wreg + SLOT(l + 64)] = g1;
        if (l < 14) {
            xs4[wreg + SLOT(l + 128)] = gw[l + 128];
        }
    } else {
        const int fb0 = n_tile0 + 512 * w;       // float base of wave window
        #pragma unroll
        for (int s = 0; s < 3; ++s) {
            const int c = l + 64 * s;            // local chunk
            if (c > 141) break;
            const int fb = fb0 + 4 * c;
            float4 v;
            v.x = (fb + 0 >= 0 && fb + 0 < n_in) ? x[fb + 0] : 0.0f;
            v.y = (fb + 1 >= 0 && fb + 1 < n_in) ? x[fb + 1] : 0.0f;
            v.z = (fb + 2 >= 0 && fb + 2 < n_in) ? x[fb + 2] : 0.0f;
            v.w = (fb + 3 >= 0 && fb + 3 < n_in) ? x[fb + 3] : 0.0f;
            xs4[wreg + SLOT(c)] = v;
        }
    }

    float a0 = 0.f, a1 = 0.f, a2 = 0.f, a3  = 0.f, a4  = 0.f, a5  = 0.f;
    float a6 = 0.f, a7 = 0.f, a8 = 0.f, a9  = 0.f, a10 = 0.f, a11 = 0.f;

    // ---- compute: 6-reg rotating window over local chunks 2l+15 .. 2l ----
#define XS(j) xs4[wreg + SLOT(2 * l + (j))]
    {
        float4 r0 = XS(15), r1 = XS(14), r2 = XS(13),
               r3 = XS(12), r4 = XS(11), r5 = XS(10);
        GRP12( 0, r0, r1, r2, r3);  r0 = XS(9);
        GRP12( 1, r1, r2, r3, r4);  r1 = XS(8);
        GRP12( 2, r2, r3, r4, r5);  r2 = XS(7);
        GRP12( 3, r3, r4, r5, r0);  r3 = XS(6);
        GRP12( 4, r4, r5, r0, r1);  r4 = XS(5);
        GRP12( 5, r5, r0, r1, r2);  r5 = XS(4);
        GRP12( 6, r0, r1, r2, r3);  r0 = XS(3);
        GRP12( 7, r1, r2, r3, r4);  r1 = XS(2);
        GRP12( 8, r2, r3, r4, r5);  r2 = XS(1);
        GRP12( 9, r3, r4, r5, r0);  r3 = XS(0);
        GRP12(10, r4, r5, r0, r1);
        GRP12(11, r5, r0, r1, r2);
        GRP12(12, r0, r1, r2, r3);
        GRP12T(13, r1, r2, r3);
    }
#undef XS

    // ---- store 12 outputs ----
    const int ob = o0 + RPT * tid;               // multiple of 12
    if (ob >= 50 && ob + 11 < n_out) {
        float4* o4 = (float4*)(out + ob);        // 16B aligned (ob % 4 == 0)
        o4[0] = make_float4(a0, a1, a2,  a3);
        o4[1] = make_float4(a4, a5, a6,  a7);
        o4[2] = make_float4(a8, a9, a10, a11);
    } else {
        const float accs[RPT] = {a0, a1, a2, a3, a4, a5, a6, a7, a8, a9, a10, a11};
#pragma unroll
        for (int d = 0; d < RPT; ++d) {
            const int o = ob + d;
            if (o >= 50 && o < n_out) out[o] = accs[d];
        }
    }
}

extern "C" void kernel_launch(void* const* d_in, const int* in_sizes, int n_in_arrs,
                              void* d_out, int out_size, void* d_ws, size_t ws_size,
                              hipStream_t stream) {
    const float* x = (const float*)d_in[0];
    const float* h = (const float*)d_in[1];
    const float* b = (const float*)d_in[2];
    float* out = (float*)d_out;
    float* cp  = (float*)d_ws;                        // 3*56*4 = 672 bytes

    const int n_in  = in_sizes[0];                    // 8388608
    const int n_out = (int)((long long)n_in * 3 / 2); // 12582912

    prep_k<<<3, TPB, 0, stream>>>(x, h, b, cp, out, n_in, n_out, out_size);

    const int nblocks = (n_out + OTILE - 1) / OTILE;  // 4096
    fused_fast<<<nblocks, TPB, 0, stream>>>(x, cp, out, n_in, n_out);
}

// Round 8
// 106.379 us; speedup vs baseline: 9.5454x; 1.0094x over previous
//
#include <hip/hip_runtime.h>

// Composite-filter formulation:
//   out[o] = sum_{k=0..54} Cp[r][k] * x[n0 - k],
//     r = (2o+32) % 3, n0 = (2o+32-r)/3,
//     Cp[p][k] = C[p+3k], C[j] = sum_m b[m]*h[j-2m]
//
// R7: direct-global windows, no barrier: 46us, VALUBusy 22%.
// R8 FAILED: reg double-buffer, VGPR 128, occupancy halved, 77us.
// R9: LDS tile + XOR float4-slot swizzle, 6-reg rotating window. <42.6us.
// R10 FAILED: LDS coeff table (uniform ds_read_b128 not free) + path merge.
// R11: prep merge (3 dispatches -> 2). total 117 -> 108.9.
// R12 FAILED: opaque-VGPR coeff idx + occupancy cap -> scratch spills (946us).
//   Lesson: WRITE_SIZE explosion = spill detector.
// R13: single up-front ds burst: neutral. lgkmcnt-conflation REFUTED.
// R14: wave-autonomous staging, __syncthreads deleted. 107.4. (best)
// R15: coefficients via lane-resident VGPR table + v_readlane.
//   Invariant across R7-R14: fused ~40-46us, VALUBusy ~22% regardless of
//   window source => the stall is the constant part: 42 coefficient
//   s_load_dwordx4 re-fetches per wave inside the FMA stream (SGPR file
//   maxed at 112 -> JIT refetch, each a lgkmcnt(0) vs K$/L2 latency).
//   Fix: lane l holds cp[l], cp[l+64], cp[128+l] in 3 VGPRs;
//   __builtin_amdgcn_readlane(creg, const_lane) -> SGPR in 1 VALU op,
//   no memory. 165 readlanes replace all coeff SMEM. Bit-identical math.

#define TPB 256
#define RPT 12                    // outputs per thread
#define OTILE (TPB * RPT)         // 3072 outputs per block
#define WREG 144                  // float4 slots per wave region (144%8==0)
#define NTAPS 55
#define CPSTRIDE 56               // phase-major coeff stride (zero-padded)

#define SLOT(c) ((c) ^ (((c) >> 3) & 7))

// One dispatch, 3 independent blocks:
//   block 0: build cp[3*56] composite coefficients (same order -> bit-identical)
//   block 1: head boundary (o in [0,50))
//   block 2: tail boundary (o in [n_out, out_size))
__global__ __launch_bounds__(TPB) void prep_k(
    const float* __restrict__ x, const float* __restrict__ h,
    const float* __restrict__ b, float* __restrict__ cp,
    float* __restrict__ out, int n_in, int n_out, int out_size)
{
    __shared__ float h_s[63];
    __shared__ float b_s[51];
    __shared__ float x_s[64];
    __shared__ float u_s[50];

    const int tid = threadIdx.x;
    if (tid < 63) h_s[tid] = h[tid];
    if (tid < 51) b_s[tid] = b[tid];

    if (blockIdx.x == 0) {
        __syncthreads();
        for (int idx = tid; idx < 3 * CPSTRIDE; idx += TPB) {
            const int p = idx / CPSTRIDE;
            const int k = idx - p * CPSTRIDE;
            float acc = 0.0f;
            if (k < NTAPS) {
                const int j = p + 3 * k;
                for (int m = 0; m <= 50; ++m) {
                    const int hi = j - 2 * m;
                    if (hi >= 0 && hi <= 62) acc += b_s[m] * h_s[hi];
                }
            }
            cp[idx] = acc;
        }
    } else if (blockIdx.x == 1) {
        if (tid < 44) x_s[tid] = (tid < n_in) ? x[tid] : 0.0f;
        __syncthreads();
        if (tid < 50) {
            const int s  = 2 * tid + 32;
            const int p0 = s % 3;
            const int q  = s / 3;
            float u = 0.0f;
            #pragma unroll
            for (int i = 0; i <= 20; ++i) {
                const int xi = q - i;
                u += h_s[p0 + 3 * i] * ((xi >= 0) ? x_s[xi] : 0.0f);
            }
            u_s[tid] = u;
        }
        __syncthreads();
        if (tid < 50) {
            float acc = 0.0f;
            for (int t = 0; t <= tid; ++t) acc += b_s[tid - t] * u_s[t];
            out[tid] = acc;
        }
    } else {
        const int t0   = n_out - 50;
        const int qmin = (2 * t0 + 32) / 3;
        const int xb   = qmin - 20;
        if (tid < 64) {
            const int xi = xb + tid;
            x_s[tid] = (xi >= 0 && xi < n_in) ? x[xi] : 0.0f;
        }
        __syncthreads();
        if (tid < 50) {
            const int t  = t0 + tid;
            const int s  = 2 * t + 32;
            const int p0 = s % 3;
            const int q  = s / 3;
            const int base = q - xb;
            float u = 0.0f;
            #pragma unroll
            for (int i = 0; i <= 20; ++i)
                u += h_s[p0 + 3 * i] * x_s[base - i];
            u_s[tid] = u;
        }
        __syncthreads();
        const int n_tail = out_size - n_out;   // 96
        if (tid < n_tail) {
            float acc = 0.0f;
            for (int j = tid; j <= 49; ++j) acc += b_s[tid + 50 - j] * u_s[j];
            out[n_out + tid] = acc;
        }
    }
}

// Coefficient fetch: flat index i (compile-time constant) -> value held in
// lane (i&63) of table reg (i>>6). readlane lane arg is a literal after
// constant folding; result is wave-uniform (SGPR), used directly by v_fma.
__device__ __forceinline__ float co(const int i, const int c0,
                                    const int c1, const int c2) {
    const int ln = i & 63;
    const int v = (i < 64)  ? __builtin_amdgcn_readlane(c0, ln)
                : (i < 128) ? __builtin_amdgcn_readlane(c1, ln)
                            : __builtin_amdgcn_readlane(c2, ln);
    return __int_as_float(v);
}

// Group g covers taps k=4g..4g+3 for 12 outputs d=0..11.
// delta_d = {0,1,2,2,3,4,4,5,6,6,7,8}, phase r_d = (2+2d)%3 -> q2/q1/q0 cycle.
// Flat coeff idx: q0 = 4g+j, q1 = 56+4g+j, q2 = 112+4g+j.
#define GRP12(g, A, B, C, D) {                                          \
    const float q2x = co(112 + 4*(g), cc0, cc1, cc2);                   \
    const float q2y = co(113 + 4*(g), cc0, cc1, cc2);                   \
    const float q2z = co(114 + 4*(g), cc0, cc1, cc2);                   \
    const float q2w = co(115 + 4*(g), cc0, cc1, cc2);                   \
    const float q1x = co( 56 + 4*(g), cc0, cc1, cc2);                   \
    const float q1y = co( 57 + 4*(g), cc0, cc1, cc2);                   \
    const float q1z = co( 58 + 4*(g), cc0, cc1, cc2);                   \
    const float q1w = co( 59 + 4*(g), cc0, cc1, cc2);                   \
    const float q0x = co(      4*(g), cc0, cc1, cc2);                   \
    const float q0y = co(  1 + 4*(g), cc0, cc1, cc2);                   \
    const float q0z = co(  2 + 4*(g), cc0, cc1, cc2);                   \
    const float q0w = co(  3 + 4*(g), cc0, cc1, cc2);                   \
    /* j=0 */                                                           \
    a0  += q2x * C.z;  a1  += q1x * C.w;  a2  += q0x * B.x;             \
    a3  += q2x * B.x;  a4  += q1x * B.y;  a5  += q0x * B.z;             \
    a6  += q2x * B.z;  a7  += q1x * B.w;  a8  += q0x * A.x;             \
    a9  += q2x * A.x;  a10 += q1x * A.y;  a11 += q0x * A.z;             \
    /* j=1 */                                                           \
    a0  += q2y * C.y;  a1  += q1y * C.z;  a2  += q0y * C.w;             \
    a3  += q2y * C.w;  a4  += q1y * B.x;  a5  += q0y * B.y;             \
    a6  += q2y * B.y;  a7  += q1y * B.z;  a8  += q0y * B.w;             \
    a9  += q2y * B.w;  a10 += q1y * A.x;  a11 += q0y * A.y;             \
    /* j=2 */                                                           \
    a0  += q2z * C.x;  a1  += q1z * C.y;  a2  += q0z * C.z;             \
    a3  += q2z * C.z;  a4  += q1z * C.w;  a5  += q0z * B.x;             \
    a6  += q2z * B.x;  a7  += q1z * B.y;  a8  += q0z * B.z;             \
    a9  += q2z * B.z;  a10 += q1z * B.w;  a11 += q0z * A.x;             \
    /* j=3 */                                                           \
    a0  += q2w * D.w;  a1  += q1w * C.x;  a2  += q0w * C.y;             \
    a3  += q2w * C.y;  a4  += q1w * C.z;  a5  += q0w * C.w;             \
    a6  += q2w * C.w;  a7  += q1w * B.x;  a8  += q0w * B.y;             \
    a9  += q2w * B.y;  a10 += q1w * B.z;  a11 += q0w * B.w; }

// Tail group: j=0..2 only (k = 52,53,54).
#define GRP12T(g, A, B, C) {                                            \
    const float q2x = co(112 + 4*(g), cc0, cc1, cc2);                   \
    const float q2y = co(113 + 4*(g), cc0, cc1, cc2);                   \
    const float q2z = co(114 + 4*(g), cc0, cc1, cc2);                   \
    const float q1x = co( 56 + 4*(g), cc0, cc1, cc2);                   \
    const float q1y = co( 57 + 4*(g), cc0, cc1, cc2);                   \
    const float q1z = co( 58 + 4*(g), cc0, cc1, cc2);                   \
    const float q0x = co(      4*(g), cc0, cc1, cc2);                   \
    const float q0y = co(  1 + 4*(g), cc0, cc1, cc2);                   \
    const float q0z = co(  2 + 4*(g), cc0, cc1, cc2);                   \
    a0  += q2x * C.z;  a1  += q1x * C.w;  a2  += q0x * B.x;             \
    a3  += q2x * B.x;  a4  += q1x * B.y;  a5  += q0x * B.z;             \
    a6  += q2x * B.z;  a7  += q1x * B.w;  a8  += q0x * A.x;             \
    a9  += q2x * A.x;  a10 += q1x * A.y;  a11 += q0x * A.z;             \
    a0  += q2y * C.y;  a1  += q1y * C.z;  a2  += q0y * C.w;             \
    a3  += q2y * C.w;  a4  += q1y * B.x;  a5  += q0y * B.y;             \
    a6  += q2y * B.y;  a7  += q1y * B.z;  a8  += q0y * B.w;             \
    a9  += q2y * B.w;  a10 += q1y * A.x;  a11 += q0y * A.y;             \
    a0  += q2z * C.x;  a1  += q1z * C.y;  a2  += q0z * C.z;             \
    a3  += q2z * C.z;  a4  += q1z * C.w;  a5  += q0z * B.x;             \
    a6  += q2z * B.x;  a7  += q1z * B.y;  a8  += q0z * B.z;             \
    a9  += q2z * B.z;  a10 += q1z * B.w;  a11 += q0z * A.x; }

__global__ __launch_bounds__(TPB) void fused_fast(
    const float* __restrict__ x, const float* __restrict__ cp,
    float* __restrict__ out, int n_in, int n_out)
{
    __shared__ float4 xs4[4 * WREG];   // 9216 B, per-wave swizzled regions

    const int tid = threadIdx.x;
    const int w   = tid >> 6;                    // wave id 0..3
    const int l   = tid & 63;                    // lane
    const int bt  = blockIdx.x;
    const int o0  = bt * OTILE;                  // multiple of 3072
    const int n_tile0 = 2048 * bt - 44;          // tile x-base, multiple of 4
    const int wreg = w * WREG;                   // this wave's LDS region base

    // ---- lane-resident coefficient table: 3 VGPRs cover all 168 floats ----
    // lane l holds cp[l], cp[64+l], cp[128+l] (lanes >=40 of reg2 unused).
    const int cc0 = __float_as_int(cp[l]);
    const int cc1 = __float_as_int(cp[l + 64]);
    const int cc2 = __float_as_int(cp[(l < 40) ? (128 + l) : 128]);

    // ---- wave-autonomous staging: lane l stages local chunks l, l+64,
    //      and (l<14) l+128 of this wave's 142-chunk window [0,141].
    //      NO __syncthreads: compute reads only own-wave region.
    const bool interior = (n_tile0 >= 0) && (n_tile0 + 2104 <= n_in);
    if (interior) {
        const float4* gw = (const float4*)(x + n_tile0) + 128 * w;
        const float4 g0 = gw[l];
        const float4 g1 = gw[l + 64];
        xs4[wreg + SLOT(l)]      = g0;
        xs4[wreg + SLOT(l + 64)] = g1;
        if (l < 14) {
            xs4[wreg + SLOT(l + 128)] = gw[l + 128];
        }
    } else {
        const int fb0 = n_tile0 + 512 * w;       // float base of wave window
        #pragma unroll
        for (int s = 0; s < 3; ++s) {
            const int c = l + 64 * s;            // local chunk
            if (c > 141) break;
            const int fb = fb0 + 4 * c;
            float4 v;
            v.x = (fb + 0 >= 0 && fb + 0 < n_in) ? x[fb + 0] : 0.0f;
            v.y = (fb + 1 >= 0 && fb + 1 < n_in) ? x[fb + 1] : 0.0f;
            v.z = (fb + 2 >= 0 && fb + 2 < n_in) ? x[fb + 2] : 0.0f;
            v.w = (fb + 3 >= 0 && fb + 3 < n_in) ? x[fb + 3] : 0.0f;
            xs4[wreg + SLOT(c)] = v;
        }
    }

    float a0 = 0.f, a1 = 0.f, a2 = 0.f, a3  = 0.f, a4  = 0.f, a5  = 0.f;
    float a6 = 0.f, a7 = 0.f, a8 = 0.f, a9  = 0.f, a10 = 0.f, a11 = 0.f;

    // ---- compute: 6-reg rotating window over local chunks 2l+15 .. 2l ----
#define XS(j) xs4[wreg + SLOT(2 * l + (j))]
    {
        float4 r0 = XS(15), r1 = XS(14), r2 = XS(13),
               r3 = XS(12), r4 = XS(11), r5 = XS(10);
        GRP12( 0, r0, r1, r2, r3);  r0 = XS(9);
        GRP12( 1, r1, r2, r3, r4);  r1 = XS(8);
        GRP12( 2, r2, r3, r4, r5);  r2 = XS(7);
        GRP12( 3, r3, r4, r5, r0);  r3 = XS(6);
        GRP12( 4, r4, r5, r0, r1);  r4 = XS(5);
        GRP12( 5, r5, r0, r1, r2);  r5 = XS(4);
        GRP12( 6, r0, r1, r2, r3);  r0 = XS(3);
        GRP12( 7, r1, r2, r3, r4);  r1 = XS(2);
        GRP12( 8, r2, r3, r4, r5);  r2 = XS(1);
        GRP12( 9, r3, r4, r5, r0);  r3 = XS(0);
        GRP12(10, r4, r5, r0, r1);
        GRP12(11, r5, r0, r1, r2);
        GRP12(12, r0, r1, r2, r3);
        GRP12T(13, r1, r2, r3);
    }
#undef XS

    // ---- store 12 outputs ----
    const int ob = o0 + RPT * tid;               // multiple of 12
    if (ob >= 50 && ob + 11 < n_out) {
        float4* o4 = (float4*)(out + ob);        // 16B aligned (ob % 4 == 0)
        o4[0] = make_float4(a0, a1, a2,  a3);
        o4[1] = make_float4(a4, a5, a6,  a7);
        o4[2] = make_float4(a8, a9, a10, a11);
    } else {
        const float accs[RPT] = {a0, a1, a2, a3, a4, a5, a6, a7, a8, a9, a10, a11};
#pragma unroll
        for (int d = 0; d < RPT; ++d) {
            const int o = ob + d;
            if (o >= 50 && o < n_out) out[o] = accs[d];
        }
    }
}

extern "C" void kernel_launch(void* const* d_in, const int* in_sizes, int n_in_arrs,
                              void* d_out, int out_size, void* d_ws, size_t ws_size,
                              hipStream_t stream) {
    const float* x = (const float*)d_in[0];
    const float* h = (const float*)d_in[1];
    const float* b = (const float*)d_in[2];
    float* out = (float*)d_out;
    float* cp  = (float*)d_ws;                        // 3*56*4 = 672 bytes

    const int n_in  = in_sizes[0];                    // 8388608
    const int n_out = (int)((long long)n_in * 3 / 2); // 12582912

    prep_k<<<3, TPB, 0, stream>>>(x, h, b, cp, out, n_in, n_out, out_size);

    const int nblocks = (n_out + OTILE - 1) / OTILE;  // 4096
    fused_fast<<<nblocks, TPB, 0, stream>>>(x, cp, out, n_in, n_out);
}